// Round 8
// baseline (166.026 us; speedup 1.0000x reference)
//
#include <hip/hip_runtime.h>
#include <hip/hip_bf16.h>
#include <math.h>

#define B_N 8192
#define D_K 256
#define TILE 128
#define NT 512
#define NBLK 64             // B_N / TILE
#define NPAIR 2080          // NBLK*(NBLK+1)/2 upper-triangular tile pairs
#define NCLS 100
#define KEXP 28.8539008177792681f   // 20*log2(e): e^(sim-20) = 2^((dot-1)*KEXP)

typedef __attribute__((ext_vector_type(8))) short short8;
typedef __attribute__((ext_vector_type(4))) float f32x4;

__device__ __forceinline__ unsigned short f2bf(float x) {
    unsigned int u = __float_as_uint(x);
    unsigned int r = (u + 0x7FFFu + ((u >> 16) & 1u)) >> 16;
    return (unsigned short)r;
}

// async global->LDS, 16B per lane: dest = (wave-uniform) lds base + lane*16
__device__ __forceinline__ void gload_lds16(const short* g, short* l) {
    __builtin_amdgcn_global_load_lds(
        (const __attribute__((address_space(1))) void*)g,
        (__attribute__((address_space(3))) void*)l, 16, 0, 0);
}

// -------- Kernel 1: normalize rows -> bf16; block 0 also: label hist + zero accums --------
__global__ void prep_kernel(const float* __restrict__ feat, unsigned short* __restrict__ fnorm,
                            const int* __restrict__ labels, int* __restrict__ cnt,
                            float* __restrict__ gscal, double* __restrict__ accum,
                            unsigned int* __restrict__ done) {
    if (blockIdx.x == 0) {
        __shared__ int h[NCLS];
        int t = threadIdx.x;
        if (t < NCLS) h[t] = 0;
        if (t == 0) {
            gscal[0] = 0.f; gscal[1] = 0.f;
            accum[0] = 0.0; accum[1] = 0.0; accum[2] = 0.0;
            *done = 0u;
        }
        __syncthreads();
        for (int r = t; r < B_N; r += 256) atomicAdd(&h[labels[r]], 1);
        __syncthreads();
        if (t < NCLS) cnt[t] = h[t];
    }
    int wave = threadIdx.x >> 6, lane = threadIdx.x & 63;
    int row = blockIdx.x * 4 + wave;
    float4 v = *(const float4*)(feat + (size_t)row * D_K + lane * 4);
    float ss = v.x * v.x + v.y * v.y + v.z * v.z + v.w * v.w;
    #pragma unroll
    for (int off = 1; off < 64; off <<= 1) ss += __shfl_xor(ss, off);
    float inv = 1.0f / fmaxf(sqrtf(ss), 1e-12f);
    ushort4 o;
    o.x = f2bf(v.x * inv); o.y = f2bf(v.y * inv);
    o.z = f2bf(v.z * inv); o.w = f2bf(v.w * inv);
    *(ushort4*)(fnorm + (size_t)row * D_K + lane * 4) = o;
}

// -------- Kernel 2: upper-triangular sim tiles; shuffle epilogue; 3 blocks/CU --------
// Staging LDS[r][c] = global chunk (c ^ (r&7)): XOR swizzle keeps global_load_lds linear
// while making fragment reads conflict-free.
__global__ __launch_bounds__(NT, 6) void main_kernel(
        const unsigned short* __restrict__ fnorm, const int* __restrict__ labels,
        float2* __restrict__ G, float* __restrict__ gscal) {
    int bid = blockIdx.x;
    int b = (int)((sqrtf(8.0f * bid + 1.0f) - 1.0f) * 0.5f);
    while ((b + 1) * (b + 2) / 2 <= bid) ++b;
    while (b * (b + 1) / 2 > bid) --b;
    int a = bid - b * (b + 1) / 2;
    const int row0 = a * TILE, col0 = b * TILE;
    const bool diag = (a == b);

    __shared__ short As[TILE * 64];    // 16 KB; reused as Rbuf float2[4][128] in epilogue
    __shared__ short Bs[TILE * 64];    // 16 KB; reused as Cbuf float2[2][128]
    __shared__ int Ls[2 * TILE];
    __shared__ int ghs[8];
    __shared__ float gps[8];

    const int tid = threadIdx.x;
    const int lane = tid & 63, wave = tid >> 6;
    const int wm = wave >> 2, wn = wave & 3;    // 2 (row) x 4 (col) waves; each 64x32
    const int l15 = lane & 15, lhi = lane >> 4;
    const short* fn = (const short*)fnorm;

    if (tid < 128) Ls[tid] = labels[row0 + tid];
    else if (tid < 256) Ls[tid] = labels[col0 + tid - 128];
    if (lane == 0) ghs[wave] = 0;

    f32x4 acc[4][2];
    #pragma unroll
    for (int i = 0; i < 4; i++)
        #pragma unroll
        for (int j = 0; j < 2; j++) acc[i][j] = {0.f, 0.f, 0.f, 0.f};

    for (int kc = 0; kc < 4; ++kc) {
        #pragma unroll
        for (int li = 0; li < 2; ++li) {
            int id = tid + li * NT;            // 0..1023: 128 rows x 8 chunks of 16B
            int r = id >> 3, c = id & 7;
            int cs = c ^ (r & 7);              // swizzled source chunk
            int ub = (id & ~63) * 8;           // wave-uniform LDS short offset
            gload_lds16(fn + (size_t)(row0 + r) * D_K + kc * 64 + cs * 8, &As[ub]);
            if (!diag)
                gload_lds16(fn + (size_t)(col0 + r) * D_K + kc * 64 + cs * 8, &Bs[ub]);
        }
        __syncthreads();
        const short* Bsrc = diag ? As : Bs;
        #pragma unroll
        for (int ks = 0; ks < 2; ++ks) {
            // load B frags first, A frags inside the mi loop: peak frag regs 12 not 24
            short8 bfr[2];
            #pragma unroll
            for (int ni = 0; ni < 2; ni++) {
                int row = wn * 32 + ni * 16 + l15;
                int ch = (ks * 4 + lhi) ^ (l15 & 7);
                bfr[ni] = *(const short8*)&Bsrc[row * 64 + ch * 8];
            }
            #pragma unroll
            for (int mi = 0; mi < 4; mi++) {
                int row = wm * 64 + mi * 16 + l15;
                int ch = (ks * 4 + lhi) ^ (l15 & 7);
                short8 af = *(const short8*)&As[row * 64 + ch * 8];
                #pragma unroll
                for (int ni = 0; ni < 2; ni++)
                    acc[mi][ni] = __builtin_amdgcn_mfma_f32_16x16x32_bf16(af, bfr[ni], acc[mi][ni], 0, 0, 0);
            }
        }
        __syncthreads();
    }

    // ---- Epilogue. C/D layout: col = lane&15, row = (lane>>4)*4 + reg ----
    float2* Rbuf = (float2*)As;   // [wn 0..3][128]
    float2* Cbuf = (float2*)Bs;   // [wm 0..1][128]

    int lc[2], colg[2];
    #pragma unroll
    for (int ni = 0; ni < 2; ni++) {
        int c = wn * 32 + ni * 16 + l15;
        lc[ni] = Ls[128 + c];
        colg[ni] = col0 + c;
    }

    float cD[2] = {0.f, 0.f};
    float gp = 0.f;           // sum of positive-pair dots (this tile)
    unsigned int hmask = 0;   // bit (pair*2+ni) = high

    #pragma unroll
    for (int mi = 0; mi < 4; mi++) {
        #pragma unroll
        for (int reg = 0; reg < 4; reg++) {
            int rloc = wm * 64 + mi * 16 + lhi * 4 + reg;
            int rowg = row0 + rloc;
            int lr = Ls[rloc];
            float d = 0.f;
            #pragma unroll
            for (int ni = 0; ni < 2; ni++) {
                float dot = acc[mi][ni][reg];
                float e = __builtin_exp2f((dot - 1.0f) * KEXP);   // e^(sim-20), sim<=20
                bool ns = (rowg != colg[ni]);
                float ev = ns ? e : 0.f;
                d += ev; cD[ni] += ev;
                bool ps = ns && (lr == lc[ni]);
                gp += ps ? dot : 0.f;
                bool hi = ps && (dot > 0.7f);
                hmask |= hi ? (1u << ((mi * 4 + reg) * 2 + ni)) : 0u;
            }
            #pragma unroll
            for (int off = 1; off < 16; off <<= 1) d += __shfl_xor(d, off);
            if (l15 == 0) Rbuf[wn * 128 + rloc] = {d, 0.f};
        }
    }

    if (!diag) {
        #pragma unroll
        for (int ni = 0; ni < 2; ni++) {
            cD[ni] += __shfl_xor(cD[ni], 16);
            cD[ni] += __shfl_xor(cD[ni], 32);
        }
        if (lhi == 0) {
            #pragma unroll
            for (int ni = 0; ni < 2; ni++)
                Cbuf[wm * 128 + wn * 32 + ni * 16 + l15] = {cD[ni], 0.f};
        }
    }

    // gp wave reduction
    #pragma unroll
    for (int off = 1; off < 64; off <<= 1) gp += __shfl_xor(gp, off);
    if (lane == 0) gps[wave] = gp;

    // ---- Rare path: any high-similarity positive in this wave ----
    if (__any(hmask != 0)) {
        float cR[2] = {0.f, 0.f};
        #pragma unroll
        for (int mi = 0; mi < 4; mi++) {
            #pragma unroll
            for (int reg = 0; reg < 4; reg++) {
                int rloc = wm * 64 + mi * 16 + lhi * 4 + reg;
                float rx = 0.f;
                #pragma unroll
                for (int ni = 0; ni < 2; ni++) {
                    if (hmask & (1u << ((mi * 4 + reg) * 2 + ni))) {
                        float e = __builtin_exp2f((acc[mi][ni][reg] - 1.0f) * KEXP);
                        rx += e; cR[ni] += e;
                    }
                }
                #pragma unroll
                for (int off = 1; off < 16; off <<= 1) rx += __shfl_xor(rx, off);
                if (l15 == 0) Rbuf[wn * 128 + rloc].y = rx;
            }
        }
        if (!diag) {
            #pragma unroll
            for (int ni = 0; ni < 2; ni++) {
                cR[ni] += __shfl_xor(cR[ni], 16);
                cR[ni] += __shfl_xor(cR[ni], 32);
            }
            if (lhi == 0) {
                #pragma unroll
                for (int ni = 0; ni < 2; ni++)
                    Cbuf[wm * 128 + wn * 32 + ni * 16 + l15].y = cR[ni];
            }
        }
        int nhi = __popc(hmask);
        #pragma unroll
        for (int off = 1; off < 64; off <<= 1) nhi += __shfl_xor(nhi, off);
        if (lane == 0) ghs[wave] = nhi;
    }
    __syncthreads();

    if (tid < 128) {
        int r = tid;
        float2 a0 = Rbuf[r], a1 = Rbuf[128 + r], a2 = Rbuf[256 + r], a3 = Rbuf[384 + r];
        G[(size_t)b * B_N + row0 + r] = {a0.x + a1.x + a2.x + a3.x, a0.y + a1.y + a2.y + a3.y};
    } else if (tid < 256 && !diag) {
        int c = tid - 128;
        float2 a0 = Cbuf[c], a1 = Cbuf[128 + c];
        G[(size_t)a * B_N + col0 + c] = {a0.x + a1.x, a0.y + a1.y};
    }
    if (tid == 0) {
        float w = diag ? 1.0f : 2.0f;   // off-diag tile stands for (i,j) and (j,i)
        float gpt = gps[0] + gps[1] + gps[2] + gps[3] + gps[4] + gps[5] + gps[6] + gps[7];
        atomicAdd(&gscal[0], w * gpt);
        int tot = ghs[0] + ghs[1] + ghs[2] + ghs[3] + ghs[4] + ghs[5] + ghs[6] + ghs[7];
        if (tot > 0) atomicAdd(&gscal[1], w * (float)tot);
    }
}

// -------- Kernel 3: per-row reduction over 64 slots + last-block final assembly --------
__global__ void finalize_kernel(const float2* __restrict__ G, const int* __restrict__ labels,
                                const int* __restrict__ cnt, const float* __restrict__ gscal,
                                double* __restrict__ accum, unsigned int* __restrict__ done,
                                float* __restrict__ out) {
    int lane = threadIdx.x & 63, q = threadIdx.x >> 6;   // q = slot quarter
    int r = blockIdx.x * 64 + lane;
    float d = 0.f, rx = 0.f;
    #pragma unroll
    for (int s = 0; s < 16; ++s) {
        float2 g = G[(size_t)(q * 16 + s) * B_N + r];
        d += g.x; rx += g.y;
    }
    __shared__ float2 sh[4][64];
    sh[q][lane] = {d, rx};
    __syncthreads();
    if (threadIdx.x < 64) {
        int rr = blockIdx.x * 64 + threadIdx.x;
        float2 t0 = sh[0][threadIdx.x], t1 = sh[1][threadIdx.x];
        float2 t2 = sh[2][threadIdx.x], t3 = sh[3][threadIdx.x];
        float dd = t0.x + t1.x + t2.x + t3.x;
        float rr2 = t0.y + t1.y + t2.y + t3.y;
        float np = (float)(cnt[labels[rr]] - 1);
        float ld = logf(dd + 1e-12f) + 20.0f;             // log_denom (shift 20)
        double s1 = (double)np * (double)ld;
        double s2 = (double)np;
        double s3 = (rr2 > 0.f) ? (double)logf(rr2 + 1.0f) : 0.0;  // baseline=0: sim_max=20
        #pragma unroll
        for (int off = 1; off < 64; off <<= 1) {
            s1 += __shfl_xor(s1, off);
            s2 += __shfl_xor(s2, off);
            s3 += __shfl_xor(s3, off);
        }
        if (threadIdx.x == 0) {
            atomicAdd(&accum[0], s1);
            atomicAdd(&accum[1], s2);
            atomicAdd(&accum[2], s3);
            __threadfence();
            unsigned int tk = atomicAdd(done, 1u);
            if (tk == gridDim.x - 1) {           // last block assembles the scalar
                double a1 = atomicAdd(&accum[0], 0.0);
                double a2 = atomicAdd(&accum[1], 0.0);
                double a3 = atomicAdd(&accum[2], 0.0);
                double gp = (double)gscal[0];    // sum over ordered pos pairs of dot
                double gh = (double)gscal[1];    // count of high ordered pairs
                double scl = (a2 > 0.0) ? (a1 - 20.0 * gp) / fmax(a2, 1.0) : 0.0;
                double rel = (gh > 0.0) ? a3 / fmax(gh, 1.0) : 0.0;
                double tot = scl + rel;          // BETA = 1.0
                tot = fmin(fmax(tot, 0.0), 10.0);
                out[0] = (float)tot;
            }
        }
    }
}

extern "C" void kernel_launch(void* const* d_in, const int* in_sizes, int n_in,
                              void* d_out, int out_size, void* d_ws, size_t ws_size,
                              hipStream_t stream) {
    const float* feat = (const float*)d_in[0];
    const int* labels = (const int*)d_in[1];
    float* out = (float*)d_out;
    char* ws = (char*)d_ws;

    unsigned short* fnorm = (unsigned short*)(ws);                          // 4 MB
    float2* G          = (float2*)(ws + (size_t)4 * 1024 * 1024);           // 4 MB: [64][8192]
    int*    cnt        = (int*)(ws + (size_t)8 * 1024 * 1024);              // 400 B
    float*  gscal      = (float*)(ws + (size_t)8 * 1024 * 1024 + 1024);     // 8 B
    double* accum      = (double*)(ws + (size_t)8 * 1024 * 1024 + 2048);    // 24 B
    unsigned int* done = (unsigned int*)(ws + (size_t)8 * 1024 * 1024 + 3072); // 4 B

    prep_kernel<<<B_N / 4, 256, 0, stream>>>(feat, fnorm, labels, cnt, gscal, accum, done);
    main_kernel<<<NPAIR, NT, 0, stream>>>(fnorm, labels, G, gscal);
    finalize_kernel<<<B_N / 64, 256, 0, stream>>>(G, labels, cnt, gscal, accum, done, out);
    (void)in_sizes; (void)n_in; (void)out_size; (void)ws_size;
}

// Round 9
// 156.771 us; speedup vs baseline: 1.0590x; 1.0590x over previous
//
#include <hip/hip_runtime.h>
#include <hip/hip_bf16.h>
#include <math.h>

#define B_N 8192
#define D_K 256
#define TILE 128
#define NT 256
#define NBLK 64             // B_N / TILE
#define NPAIR 2080          // NBLK*(NBLK+1)/2 upper-triangular tile pairs
#define NCLS 100
#define KEXP 28.8539008177792681f   // 20*log2(e): e^(sim-20) = 2^((dot-1)*KEXP)

typedef __attribute__((ext_vector_type(8))) short short8;
typedef __attribute__((ext_vector_type(4))) float f32x4;

__device__ __forceinline__ unsigned short f2bf(float x) {
    unsigned int u = __float_as_uint(x);
    unsigned int r = (u + 0x7FFFu + ((u >> 16) & 1u)) >> 16;
    return (unsigned short)r;
}

// async global->LDS, 16B per lane: dest = (wave-uniform) lds base + lane*16
__device__ __forceinline__ void gload_lds16(const short* g, short* l) {
    __builtin_amdgcn_global_load_lds(
        (const __attribute__((address_space(1))) void*)g,
        (__attribute__((address_space(3))) void*)l, 16, 0, 0);
}

// sum over each aligned 16-lane group, entirely on the VALU pipe (DPP).
// quad_perm[1,0,3,2]=0xB1, quad_perm[2,3,0,1]=0x4E, row_half_mirror=0x141, row_mirror=0x140
__device__ __forceinline__ float row_sum16(float v) {
    v += __int_as_float(__builtin_amdgcn_update_dpp(0, __float_as_int(v), 0xB1, 0xF, 0xF, true));
    v += __int_as_float(__builtin_amdgcn_update_dpp(0, __float_as_int(v), 0x4E, 0xF, 0xF, true));
    v += __int_as_float(__builtin_amdgcn_update_dpp(0, __float_as_int(v), 0x141, 0xF, 0xF, true));
    v += __int_as_float(__builtin_amdgcn_update_dpp(0, __float_as_int(v), 0x140, 0xF, 0xF, true));
    return v;
}

// -------- Kernel 1: normalize rows -> bf16; block 0 also: label hist + zero accums --------
__global__ void prep_kernel(const float* __restrict__ feat, unsigned short* __restrict__ fnorm,
                            const int* __restrict__ labels, int* __restrict__ cnt,
                            float* __restrict__ gscal, double* __restrict__ accum,
                            unsigned int* __restrict__ done) {
    if (blockIdx.x == 0) {
        __shared__ int h[NCLS];
        int t = threadIdx.x;
        if (t < NCLS) h[t] = 0;
        if (t == 0) {
            gscal[0] = 0.f; gscal[1] = 0.f;
            accum[0] = 0.0; accum[1] = 0.0; accum[2] = 0.0;
            *done = 0u;
        }
        __syncthreads();
        for (int r = t; r < B_N; r += 256) atomicAdd(&h[labels[r]], 1);
        __syncthreads();
        if (t < NCLS) cnt[t] = h[t];
    }
    int wave = threadIdx.x >> 6, lane = threadIdx.x & 63;
    int row = blockIdx.x * 4 + wave;
    float4 v = *(const float4*)(feat + (size_t)row * D_K + lane * 4);
    float ss = v.x * v.x + v.y * v.y + v.z * v.z + v.w * v.w;
    #pragma unroll
    for (int off = 1; off < 64; off <<= 1) ss += __shfl_xor(ss, off);
    float inv = 1.0f / fmaxf(sqrtf(ss), 1e-12f);
    ushort4 o;
    o.x = f2bf(v.x * inv); o.y = f2bf(v.y * inv);
    o.z = f2bf(v.z * inv); o.w = f2bf(v.w * inv);
    *(ushort4*)(fnorm + (size_t)row * D_K + lane * 4) = o;
}

// -------- Kernel 2: upper-triangular sim tiles; 4 waves x 64x64; DPP epilogue --------
// Staging LDS[r][c] = global chunk (c ^ (r&7)): XOR swizzle keeps global_load_lds linear
// while making fragment reads conflict-free.
__global__ __launch_bounds__(NT, 4) void main_kernel(
        const unsigned short* __restrict__ fnorm, const int* __restrict__ labels,
        float2* __restrict__ G, float* __restrict__ gscal) {
    int bid = blockIdx.x;
    int b = (int)((sqrtf(8.0f * bid + 1.0f) - 1.0f) * 0.5f);
    while ((b + 1) * (b + 2) / 2 <= bid) ++b;
    while (b * (b + 1) / 2 > bid) --b;
    int a = bid - b * (b + 1) / 2;
    const int row0 = a * TILE, col0 = b * TILE;
    const bool diag = (a == b);

    __shared__ short As[TILE * 64];    // 16 KB; reused as Rbuf float2[2][128] in epilogue
    __shared__ short Bs[TILE * 64];    // 16 KB; reused as Cbuf float2[2][128]
    __shared__ int Ls[2 * TILE];
    __shared__ int ghs[4];
    __shared__ float gps[4];

    const int tid = threadIdx.x;
    const int lane = tid & 63, wave = tid >> 6;
    const int wm = wave >> 1, wn = wave & 1;    // 2x2 waves; each 64x64
    const int l15 = lane & 15, lhi = lane >> 4;
    const short* fn = (const short*)fnorm;

    if (tid < 128) Ls[tid] = labels[row0 + tid];
    else Ls[tid] = labels[col0 + tid - 128];
    if (lane == 0) ghs[wave] = 0;

    f32x4 acc[4][4];
    #pragma unroll
    for (int i = 0; i < 4; i++)
        #pragma unroll
        for (int j = 0; j < 4; j++) acc[i][j] = {0.f, 0.f, 0.f, 0.f};

    for (int kc = 0; kc < 4; ++kc) {
        #pragma unroll
        for (int li = 0; li < 4; ++li) {
            int id = tid + li * NT;            // 0..1023: 128 rows x 8 chunks of 16B
            int r = id >> 3, c = id & 7;
            int cs = c ^ (r & 7);              // swizzled source chunk
            int ub = (id & ~63) * 8;           // wave-uniform LDS short offset
            gload_lds16(fn + (size_t)(row0 + r) * D_K + kc * 64 + cs * 8, &As[ub]);
            if (!diag)
                gload_lds16(fn + (size_t)(col0 + r) * D_K + kc * 64 + cs * 8, &Bs[ub]);
        }
        __syncthreads();
        const short* Bsrc = diag ? As : Bs;
        #pragma unroll
        for (int ks = 0; ks < 2; ++ks) {
            short8 bfr[4];
            #pragma unroll
            for (int ni = 0; ni < 4; ni++) {
                int row = wn * 64 + ni * 16 + l15;
                int ch = (ks * 4 + lhi) ^ (l15 & 7);
                bfr[ni] = *(const short8*)&Bsrc[row * 64 + ch * 8];
            }
            #pragma unroll
            for (int mi = 0; mi < 4; mi++) {
                int row = wm * 64 + mi * 16 + l15;
                int ch = (ks * 4 + lhi) ^ (l15 & 7);
                short8 af = *(const short8*)&As[row * 64 + ch * 8];
                #pragma unroll
                for (int ni = 0; ni < 4; ni++)
                    acc[mi][ni] = __builtin_amdgcn_mfma_f32_16x16x32_bf16(af, bfr[ni], acc[mi][ni], 0, 0, 0);
            }
        }
        __syncthreads();
    }

    // ---- Epilogue. C/D layout: col = lane&15, row = (lane>>4)*4 + reg ----
    float2* Rbuf = (float2*)As;   // [wn 0..1][128]
    float2* Cbuf = (float2*)Bs;   // [wm 0..1][128]

    int lc[4], colg[4];
    #pragma unroll
    for (int ni = 0; ni < 4; ni++) {
        int c = wn * 64 + ni * 16 + l15;
        lc[ni] = Ls[128 + c];
        colg[ni] = col0 + c;
    }

    float cD[4] = {0.f, 0.f, 0.f, 0.f};
    float gp = 0.f;                  // sum of positive-pair dots (this tile)
    unsigned long long hmask = 0ull; // bit ((mi*4+reg)*4+ni) = high

    #pragma unroll
    for (int mi = 0; mi < 4; mi++) {
        #pragma unroll
        for (int reg = 0; reg < 4; reg++) {
            int rloc = wm * 64 + mi * 16 + lhi * 4 + reg;
            int rowg = row0 + rloc;
            int lr = Ls[rloc];
            float d = 0.f;
            #pragma unroll
            for (int ni = 0; ni < 4; ni++) {
                float dot = acc[mi][ni][reg];
                float e = __builtin_exp2f((dot - 1.0f) * KEXP);   // e^(sim-20), sim<=20
                bool ns = (rowg != colg[ni]);
                float ev = ns ? e : 0.f;
                d += ev; cD[ni] += ev;
                bool ps = ns && (lr == lc[ni]);
                gp += ps ? dot : 0.f;
                bool hi = ps && (dot > 0.7f);
                hmask |= hi ? (1ull << ((mi * 4 + reg) * 4 + ni)) : 0ull;
            }
            d = row_sum16(d);                  // VALU-pipe DPP butterfly
            if (l15 == 0) Rbuf[wn * 128 + rloc] = {d, 0.f};
        }
    }

    if (!diag) {
        #pragma unroll
        for (int ni = 0; ni < 4; ni++) {
            cD[ni] += __shfl_xor(cD[ni], 16);
            cD[ni] += __shfl_xor(cD[ni], 32);
        }
        if (lhi == 0) {
            #pragma unroll
            for (int ni = 0; ni < 4; ni++)
                Cbuf[wm * 128 + wn * 64 + ni * 16 + l15] = {cD[ni], 0.f};
        }
    }

    // gp wave reduction
    gp = row_sum16(gp);
    gp += __shfl_xor(gp, 16);
    gp += __shfl_xor(gp, 32);
    if (lane == 0) gps[wave] = gp;

    // ---- Rare path: any high-similarity positive in this wave ----
    if (__any(hmask != 0ull)) {
        float cR[4] = {0.f, 0.f, 0.f, 0.f};
        #pragma unroll
        for (int mi = 0; mi < 4; mi++) {
            #pragma unroll
            for (int reg = 0; reg < 4; reg++) {
                int rloc = wm * 64 + mi * 16 + lhi * 4 + reg;
                float rx = 0.f;
                #pragma unroll
                for (int ni = 0; ni < 4; ni++) {
                    if (hmask & (1ull << ((mi * 4 + reg) * 4 + ni))) {
                        float e = __builtin_exp2f((acc[mi][ni][reg] - 1.0f) * KEXP);
                        rx += e; cR[ni] += e;
                    }
                }
                rx = row_sum16(rx);
                if (l15 == 0) Rbuf[wn * 128 + rloc].y = rx;
            }
        }
        if (!diag) {
            #pragma unroll
            for (int ni = 0; ni < 4; ni++) {
                cR[ni] += __shfl_xor(cR[ni], 16);
                cR[ni] += __shfl_xor(cR[ni], 32);
            }
            if (lhi == 0) {
                #pragma unroll
                for (int ni = 0; ni < 4; ni++)
                    Cbuf[wm * 128 + wn * 64 + ni * 16 + l15].y = cR[ni];
            }
        }
        int nhi = __popcll(hmask);
        #pragma unroll
        for (int off = 1; off < 64; off <<= 1) nhi += __shfl_xor(nhi, off);
        if (lane == 0) ghs[wave] = nhi;
    }
    __syncthreads();

    if (tid < 128) {
        int r = tid;
        float2 a0 = Rbuf[r], a1 = Rbuf[128 + r];
        G[(size_t)b * B_N + row0 + r] = {a0.x + a1.x, a0.y + a1.y};
    } else if (!diag) {
        int c = tid - 128;
        float2 a0 = Cbuf[c], a1 = Cbuf[128 + c];
        G[(size_t)a * B_N + col0 + c] = {a0.x + a1.x, a0.y + a1.y};
    }
    if (tid == 0) {
        float w = diag ? 1.0f : 2.0f;   // off-diag tile stands for (i,j) and (j,i)
        float gpt = gps[0] + gps[1] + gps[2] + gps[3];
        atomicAdd(&gscal[0], w * gpt);
        int tot = ghs[0] + ghs[1] + ghs[2] + ghs[3];
        if (tot > 0) atomicAdd(&gscal[1], w * (float)tot);
    }
}

// -------- Kernel 3: per-row reduction over 64 slots + last-block final assembly --------
__global__ void finalize_kernel(const float2* __restrict__ G, const int* __restrict__ labels,
                                const int* __restrict__ cnt, const float* __restrict__ gscal,
                                double* __restrict__ accum, unsigned int* __restrict__ done,
                                float* __restrict__ out) {
    int lane = threadIdx.x & 63, q = threadIdx.x >> 6;   // q = slot quarter
    int r = blockIdx.x * 64 + lane;
    float d = 0.f, rx = 0.f;
    #pragma unroll
    for (int s = 0; s < 16; ++s) {
        float2 g = G[(size_t)(q * 16 + s) * B_N + r];
        d += g.x; rx += g.y;
    }
    __shared__ float2 sh[4][64];
    sh[q][lane] = {d, rx};
    __syncthreads();
    if (threadIdx.x < 64) {
        int rr = blockIdx.x * 64 + threadIdx.x;
        float2 t0 = sh[0][threadIdx.x], t1 = sh[1][threadIdx.x];
        float2 t2 = sh[2][threadIdx.x], t3 = sh[3][threadIdx.x];
        float dd = t0.x + t1.x + t2.x + t3.x;
        float rr2 = t0.y + t1.y + t2.y + t3.y;
        float np = (float)(cnt[labels[rr]] - 1);
        float ld = logf(dd + 1e-12f) + 20.0f;             // log_denom (shift 20)
        double s1 = (double)np * (double)ld;
        double s2 = (double)np;
        double s3 = (rr2 > 0.f) ? (double)logf(rr2 + 1.0f) : 0.0;  // baseline=0: sim_max=20
        #pragma unroll
        for (int off = 1; off < 64; off <<= 1) {
            s1 += __shfl_xor(s1, off);
            s2 += __shfl_xor(s2, off);
            s3 += __shfl_xor(s3, off);
        }
        if (threadIdx.x == 0) {
            atomicAdd(&accum[0], s1);
            atomicAdd(&accum[1], s2);
            atomicAdd(&accum[2], s3);
            __threadfence();
            unsigned int tk = atomicAdd(done, 1u);
            if (tk == gridDim.x - 1) {           // last block assembles the scalar
                double a1 = atomicAdd(&accum[0], 0.0);
                double a2 = atomicAdd(&accum[1], 0.0);
                double a3 = atomicAdd(&accum[2], 0.0);
                double gp = (double)gscal[0];    // sum over ordered pos pairs of dot
                double gh = (double)gscal[1];    // count of high ordered pairs
                double scl = (a2 > 0.0) ? (a1 - 20.0 * gp) / fmax(a2, 1.0) : 0.0;
                double rel = (gh > 0.0) ? a3 / fmax(gh, 1.0) : 0.0;
                double tot = scl + rel;          // BETA = 1.0
                tot = fmin(fmax(tot, 0.0), 10.0);
                out[0] = (float)tot;
            }
        }
    }
}

extern "C" void kernel_launch(void* const* d_in, const int* in_sizes, int n_in,
                              void* d_out, int out_size, void* d_ws, size_t ws_size,
                              hipStream_t stream) {
    const float* feat = (const float*)d_in[0];
    const int* labels = (const int*)d_in[1];
    float* out = (float*)d_out;
    char* ws = (char*)d_ws;

    unsigned short* fnorm = (unsigned short*)(ws);                          // 4 MB
    float2* G          = (float2*)(ws + (size_t)4 * 1024 * 1024);           // 4 MB: [64][8192]
    int*    cnt        = (int*)(ws + (size_t)8 * 1024 * 1024);              // 400 B
    float*  gscal      = (float*)(ws + (size_t)8 * 1024 * 1024 + 1024);     // 8 B
    double* accum      = (double*)(ws + (size_t)8 * 1024 * 1024 + 2048);    // 24 B
    unsigned int* done = (unsigned int*)(ws + (size_t)8 * 1024 * 1024 + 3072); // 4 B

    prep_kernel<<<B_N / 4, 256, 0, stream>>>(feat, fnorm, labels, cnt, gscal, accum, done);
    main_kernel<<<NPAIR, NT, 0, stream>>>(fnorm, labels, G, gscal);
    finalize_kernel<<<B_N / 64, 256, 0, stream>>>(G, labels, cnt, gscal, accum, done, out);
    (void)in_sizes; (void)n_in; (void)out_size; (void)ws_size;
}

// Round 10
// 124.090 us; speedup vs baseline: 1.3379x; 1.2634x over previous
//
#include <hip/hip_runtime.h>
#include <hip/hip_bf16.h>
#include <math.h>

#define B_N 8192
#define D_K 256
#define TILE 128
#define NT 512
#define NBLK 64             // B_N / TILE
#define NPAIR 2080          // NBLK*(NBLK+1)/2 upper-triangular tile pairs
#define NCLS 100
#define KEXP 28.8539008177792681f   // 20*log2(e): e^(sim-20) = 2^((dot-1)*KEXP)

typedef __attribute__((ext_vector_type(8))) short short8;
typedef __attribute__((ext_vector_type(4))) float f32x4;

__device__ __forceinline__ unsigned short f2bf(float x) {
    unsigned int u = __float_as_uint(x);
    unsigned int r = (u + 0x7FFFu + ((u >> 16) & 1u)) >> 16;
    return (unsigned short)r;
}

// async global->LDS, 16B per lane: dest = (wave-uniform) lds base + lane*16
__device__ __forceinline__ void gload_lds16(const short* g, short* l) {
    __builtin_amdgcn_global_load_lds(
        (const __attribute__((address_space(1))) void*)g,
        (__attribute__((address_space(3))) void*)l, 16, 0, 0);
}

// sum over each aligned 16-lane group on the VALU pipe (DPP butterfly+mirrors).
// Verified on-device in round 9 (absmax 0).
__device__ __forceinline__ float row_sum16(float v) {
    v += __int_as_float(__builtin_amdgcn_update_dpp(0, __float_as_int(v), 0xB1, 0xF, 0xF, true));
    v += __int_as_float(__builtin_amdgcn_update_dpp(0, __float_as_int(v), 0x4E, 0xF, 0xF, true));
    v += __int_as_float(__builtin_amdgcn_update_dpp(0, __float_as_int(v), 0x141, 0xF, 0xF, true));
    v += __int_as_float(__builtin_amdgcn_update_dpp(0, __float_as_int(v), 0x140, 0xF, 0xF, true));
    return v;
}

// -------- Kernel 1: normalize rows -> bf16; block 0 also: label hist + zero accums --------
__global__ void prep_kernel(const float* __restrict__ feat, unsigned short* __restrict__ fnorm,
                            const int* __restrict__ labels, int* __restrict__ cnt,
                            float* __restrict__ gscal, double* __restrict__ accum,
                            unsigned int* __restrict__ done) {
    if (blockIdx.x == 0) {
        __shared__ int h[NCLS];
        int t = threadIdx.x;
        if (t < NCLS) h[t] = 0;
        if (t == 0) {
            gscal[0] = 0.f; gscal[1] = 0.f;
            accum[0] = 0.0; accum[1] = 0.0; accum[2] = 0.0;
            *done = 0u;
        }
        __syncthreads();
        for (int r = t; r < B_N; r += 256) atomicAdd(&h[labels[r]], 1);
        __syncthreads();
        if (t < NCLS) cnt[t] = h[t];
    }
    int wave = threadIdx.x >> 6, lane = threadIdx.x & 63;
    int row = blockIdx.x * 4 + wave;
    float4 v = *(const float4*)(feat + (size_t)row * D_K + lane * 4);
    float ss = v.x * v.x + v.y * v.y + v.z * v.z + v.w * v.w;
    #pragma unroll
    for (int off = 1; off < 64; off <<= 1) ss += __shfl_xor(ss, off);
    float inv = 1.0f / fmaxf(sqrtf(ss), 1e-12f);
    ushort4 o;
    o.x = f2bf(v.x * inv); o.y = f2bf(v.y * inv);
    o.z = f2bf(v.z * inv); o.w = f2bf(v.w * inv);
    *(ushort4*)(fnorm + (size_t)row * D_K + lane * 4) = o;
}

// -------- Kernel 2: upper-triangular sim tiles; 8 waves x 64x32; DPP epilogue --------
// Staging LDS[r][c] = global chunk (c ^ (r&7)): XOR swizzle keeps global_load_lds linear
// while making fragment reads conflict-free.  (512,4): proven no-spill shape (r5).
__global__ __launch_bounds__(NT, 4) void main_kernel(
        const unsigned short* __restrict__ fnorm, const int* __restrict__ labels,
        float2* __restrict__ G, float* __restrict__ gscal) {
    int bid = blockIdx.x;
    int b = (int)((sqrtf(8.0f * bid + 1.0f) - 1.0f) * 0.5f);
    while ((b + 1) * (b + 2) / 2 <= bid) ++b;
    while (b * (b + 1) / 2 > bid) --b;
    int a = bid - b * (b + 1) / 2;
    const int row0 = a * TILE, col0 = b * TILE;
    const bool diag = (a == b);

    __shared__ short As[TILE * 64];    // 16 KB; reused as Rbuf float2[4][128] in epilogue
    __shared__ short Bs[TILE * 64];    // 16 KB; reused as Cbuf float2[2][128]
    __shared__ int Ls[2 * TILE];
    __shared__ int ghs[8];
    __shared__ float gps[8];

    const int tid = threadIdx.x;
    const int lane = tid & 63, wave = tid >> 6;
    const int wm = wave >> 2, wn = wave & 3;    // 2 (row) x 4 (col) waves; each 64x32
    const int l15 = lane & 15, lhi = lane >> 4;
    const short* fn = (const short*)fnorm;

    if (tid < 128) Ls[tid] = labels[row0 + tid];
    else if (tid < 256) Ls[tid] = labels[col0 + tid - 128];
    if (lane == 0) ghs[wave] = 0;

    f32x4 acc[4][2];
    #pragma unroll
    for (int i = 0; i < 4; i++)
        #pragma unroll
        for (int j = 0; j < 2; j++) acc[i][j] = {0.f, 0.f, 0.f, 0.f};

    for (int kc = 0; kc < 4; ++kc) {
        #pragma unroll
        for (int li = 0; li < 2; ++li) {
            int id = tid + li * NT;            // 0..1023: 128 rows x 8 chunks of 16B
            int r = id >> 3, c = id & 7;
            int cs = c ^ (r & 7);              // swizzled source chunk
            int ub = (id & ~63) * 8;           // wave-uniform LDS short offset
            gload_lds16(fn + (size_t)(row0 + r) * D_K + kc * 64 + cs * 8, &As[ub]);
            if (!diag)
                gload_lds16(fn + (size_t)(col0 + r) * D_K + kc * 64 + cs * 8, &Bs[ub]);
        }
        __syncthreads();
        const short* Bsrc = diag ? As : Bs;
        #pragma unroll
        for (int ks = 0; ks < 2; ++ks) {
            short8 af[4], bfr[2];
            #pragma unroll
            for (int mi = 0; mi < 4; mi++) {
                int row = wm * 64 + mi * 16 + l15;
                int ch = (ks * 4 + lhi) ^ (l15 & 7);
                af[mi] = *(const short8*)&As[row * 64 + ch * 8];
            }
            #pragma unroll
            for (int ni = 0; ni < 2; ni++) {
                int row = wn * 32 + ni * 16 + l15;
                int ch = (ks * 4 + lhi) ^ (l15 & 7);
                bfr[ni] = *(const short8*)&Bsrc[row * 64 + ch * 8];
            }
            #pragma unroll
            for (int mi = 0; mi < 4; mi++)
                #pragma unroll
                for (int ni = 0; ni < 2; ni++)
                    acc[mi][ni] = __builtin_amdgcn_mfma_f32_16x16x32_bf16(af[mi], bfr[ni], acc[mi][ni], 0, 0, 0);
        }
        __syncthreads();
    }

    // ---- Epilogue. C/D layout: col = lane&15, row = (lane>>4)*4 + reg ----
    float2* Rbuf = (float2*)As;   // [wn 0..3][128]
    float2* Cbuf = (float2*)Bs;   // [wm 0..1][128]

    int lc[2], colg[2];
    #pragma unroll
    for (int ni = 0; ni < 2; ni++) {
        int c = wn * 32 + ni * 16 + l15;
        lc[ni] = Ls[128 + c];
        colg[ni] = col0 + c;
    }

    float cD[2] = {0.f, 0.f};
    float gp = 0.f;           // sum of positive-pair dots (this tile)
    unsigned int hmask = 0;   // bit (pair*2+ni) = high

    #pragma unroll
    for (int mi = 0; mi < 4; mi++) {
        #pragma unroll
        for (int reg = 0; reg < 4; reg++) {
            int rloc = wm * 64 + mi * 16 + lhi * 4 + reg;
            int rowg = row0 + rloc;
            int lr = Ls[rloc];
            float d = 0.f;
            #pragma unroll
            for (int ni = 0; ni < 2; ni++) {
                float dot = acc[mi][ni][reg];
                float e = __builtin_exp2f((dot - 1.0f) * KEXP);   // e^(sim-20), sim<=20
                bool ns = (rowg != colg[ni]);
                float ev = ns ? e : 0.f;
                d += ev; cD[ni] += ev;
                bool ps = ns && (lr == lc[ni]);
                gp += ps ? dot : 0.f;
                bool hi = ps && (dot > 0.7f);
                hmask |= hi ? (1u << ((mi * 4 + reg) * 2 + ni)) : 0u;
            }
            d = row_sum16(d);                  // VALU pipe, not LDS pipe
            if (l15 == 0) Rbuf[wn * 128 + rloc] = {d, 0.f};
        }
    }

    if (!diag) {
        #pragma unroll
        for (int ni = 0; ni < 2; ni++) {
            cD[ni] += __shfl_xor(cD[ni], 16);
            cD[ni] += __shfl_xor(cD[ni], 32);
        }
        if (lhi == 0) {
            #pragma unroll
            for (int ni = 0; ni < 2; ni++)
                Cbuf[wm * 128 + wn * 32 + ni * 16 + l15] = {cD[ni], 0.f};
        }
    }

    // gp wave reduction: DPP within 16, shuffles across
    gp = row_sum16(gp);
    gp += __shfl_xor(gp, 16);
    gp += __shfl_xor(gp, 32);
    if (lane == 0) gps[wave] = gp;

    // ---- Rare path: any high-similarity positive in this wave ----
    if (__any(hmask != 0)) {
        float cR[2] = {0.f, 0.f};
        #pragma unroll
        for (int mi = 0; mi < 4; mi++) {
            #pragma unroll
            for (int reg = 0; reg < 4; reg++) {
                int rloc = wm * 64 + mi * 16 + lhi * 4 + reg;
                float rx = 0.f;
                #pragma unroll
                for (int ni = 0; ni < 2; ni++) {
                    if (hmask & (1u << ((mi * 4 + reg) * 2 + ni))) {
                        float e = __builtin_exp2f((acc[mi][ni][reg] - 1.0f) * KEXP);
                        rx += e; cR[ni] += e;
                    }
                }
                rx = row_sum16(rx);
                if (l15 == 0) Rbuf[wn * 128 + rloc].y = rx;
            }
        }
        if (!diag) {
            #pragma unroll
            for (int ni = 0; ni < 2; ni++) {
                cR[ni] += __shfl_xor(cR[ni], 16);
                cR[ni] += __shfl_xor(cR[ni], 32);
            }
            if (lhi == 0) {
                #pragma unroll
                for (int ni = 0; ni < 2; ni++)
                    Cbuf[wm * 128 + wn * 32 + ni * 16 + l15].y = cR[ni];
            }
        }
        int nhi = __popc(hmask);
        #pragma unroll
        for (int off = 1; off < 64; off <<= 1) nhi += __shfl_xor(nhi, off);
        if (lane == 0) ghs[wave] = nhi;
    }
    __syncthreads();

    if (tid < 128) {
        int r = tid;
        float2 a0 = Rbuf[r], a1 = Rbuf[128 + r], a2 = Rbuf[256 + r], a3 = Rbuf[384 + r];
        G[(size_t)b * B_N + row0 + r] = {a0.x + a1.x + a2.x + a3.x, a0.y + a1.y + a2.y + a3.y};
    } else if (tid < 256 && !diag) {
        int c = tid - 128;
        float2 a0 = Cbuf[c], a1 = Cbuf[128 + c];
        G[(size_t)a * B_N + col0 + c] = {a0.x + a1.x, a0.y + a1.y};
    }
    if (tid == 0) {
        float w = diag ? 1.0f : 2.0f;   // off-diag tile stands for (i,j) and (j,i)
        float gpt = gps[0] + gps[1] + gps[2] + gps[3] + gps[4] + gps[5] + gps[6] + gps[7];
        atomicAdd(&gscal[0], w * gpt);
        int tot = ghs[0] + ghs[1] + ghs[2] + ghs[3] + ghs[4] + ghs[5] + ghs[6] + ghs[7];
        if (tot > 0) atomicAdd(&gscal[1], w * (float)tot);
    }
}

// -------- Kernel 3: per-row reduction over 64 slots + last-block final assembly --------
__global__ void finalize_kernel(const float2* __restrict__ G, const int* __restrict__ labels,
                                const int* __restrict__ cnt, const float* __restrict__ gscal,
                                double* __restrict__ accum, unsigned int* __restrict__ done,
                                float* __restrict__ out) {
    int lane = threadIdx.x & 63, q = threadIdx.x >> 6;   // q = slot quarter
    int r = blockIdx.x * 64 + lane;
    float d = 0.f, rx = 0.f;
    #pragma unroll
    for (int s = 0; s < 16; ++s) {
        float2 g = G[(size_t)(q * 16 + s) * B_N + r];
        d += g.x; rx += g.y;
    }
    __shared__ float2 sh[4][64];
    sh[q][lane] = {d, rx};
    __syncthreads();
    if (threadIdx.x < 64) {
        int rr = blockIdx.x * 64 + threadIdx.x;
        float2 t0 = sh[0][threadIdx.x], t1 = sh[1][threadIdx.x];
        float2 t2 = sh[2][threadIdx.x], t3 = sh[3][threadIdx.x];
        float dd = t0.x + t1.x + t2.x + t3.x;
        float rr2 = t0.y + t1.y + t2.y + t3.y;
        float np = (float)(cnt[labels[rr]] - 1);
        float ld = logf(dd + 1e-12f) + 20.0f;             // log_denom (shift 20)
        double s1 = (double)np * (double)ld;
        double s2 = (double)np;
        double s3 = (rr2 > 0.f) ? (double)logf(rr2 + 1.0f) : 0.0;  // baseline=0: sim_max=20
        #pragma unroll
        for (int off = 1; off < 64; off <<= 1) {
            s1 += __shfl_xor(s1, off);
            s2 += __shfl_xor(s2, off);
            s3 += __shfl_xor(s3, off);
        }
        if (threadIdx.x == 0) {
            atomicAdd(&accum[0], s1);
            atomicAdd(&accum[1], s2);
            atomicAdd(&accum[2], s3);
            __threadfence();
            unsigned int tk = atomicAdd(done, 1u);
            if (tk == gridDim.x - 1) {           // last block assembles the scalar
                double a1 = atomicAdd(&accum[0], 0.0);
                double a2 = atomicAdd(&accum[1], 0.0);
                double a3 = atomicAdd(&accum[2], 0.0);
                double gp = (double)gscal[0];    // sum over ordered pos pairs of dot
                double gh = (double)gscal[1];    // count of high ordered pairs
                double scl = (a2 > 0.0) ? (a1 - 20.0 * gp) / fmax(a2, 1.0) : 0.0;
                double rel = (gh > 0.0) ? a3 / fmax(gh, 1.0) : 0.0;
                double tot = scl + rel;          // BETA = 1.0
                tot = fmin(fmax(tot, 0.0), 10.0);
                out[0] = (float)tot;
            }
        }
    }
}

extern "C" void kernel_launch(void* const* d_in, const int* in_sizes, int n_in,
                              void* d_out, int out_size, void* d_ws, size_t ws_size,
                              hipStream_t stream) {
    const float* feat = (const float*)d_in[0];
    const int* labels = (const int*)d_in[1];
    float* out = (float*)d_out;
    char* ws = (char*)d_ws;

    unsigned short* fnorm = (unsigned short*)(ws);                          // 4 MB
    float2* G          = (float2*)(ws + (size_t)4 * 1024 * 1024);           // 4 MB: [64][8192]
    int*    cnt        = (int*)(ws + (size_t)8 * 1024 * 1024);              // 400 B
    float*  gscal      = (float*)(ws + (size_t)8 * 1024 * 1024 + 1024);     // 8 B
    double* accum      = (double*)(ws + (size_t)8 * 1024 * 1024 + 2048);    // 24 B
    unsigned int* done = (unsigned int*)(ws + (size_t)8 * 1024 * 1024 + 3072); // 4 B

    prep_kernel<<<B_N / 4, 256, 0, stream>>>(feat, fnorm, labels, cnt, gscal, accum, done);
    main_kernel<<<NPAIR, NT, 0, stream>>>(fnorm, labels, G, gscal);
    finalize_kernel<<<B_N / 64, 256, 0, stream>>>(G, labels, cnt, gscal, accum, done, out);
    (void)in_sizes; (void)n_in; (void)out_size; (void)ws_size;
}

// Round 11
// 122.089 us; speedup vs baseline: 1.3599x; 1.0164x over previous
//
#include <hip/hip_runtime.h>
#include <hip/hip_bf16.h>
#include <math.h>

#define B_N 8192
#define D_K 256
#define TILE 128
#define NT 512
#define NBLK 64             // B_N / TILE
#define NPAIR 2080          // NBLK*(NBLK+1)/2 upper-triangular tile pairs
#define NCLS 100
#define KEXP 28.8539008177792681f   // 20*log2(e): e^(sim-20) = 2^((dot-1)*KEXP)

typedef __attribute__((ext_vector_type(8))) short short8;
typedef __attribute__((ext_vector_type(4))) float f32x4;

__device__ __forceinline__ unsigned short f2bf(float x) {
    unsigned int u = __float_as_uint(x);
    unsigned int r = (u + 0x7FFFu + ((u >> 16) & 1u)) >> 16;
    return (unsigned short)r;
}

// async global->LDS, 16B per lane: dest = (wave-uniform) lds base + lane*16
__device__ __forceinline__ void gload_lds16(const short* g, short* l) {
    __builtin_amdgcn_global_load_lds(
        (const __attribute__((address_space(1))) void*)g,
        (__attribute__((address_space(3))) void*)l, 16, 0, 0);
}

// sum over each aligned 16-lane group on the VALU pipe (DPP butterfly+mirrors).
// Verified on-device (r9/r10, absmax 0).
__device__ __forceinline__ float row_sum16(float v) {
    v += __int_as_float(__builtin_amdgcn_update_dpp(0, __float_as_int(v), 0xB1, 0xF, 0xF, true));
    v += __int_as_float(__builtin_amdgcn_update_dpp(0, __float_as_int(v), 0x4E, 0xF, 0xF, true));
    v += __int_as_float(__builtin_amdgcn_update_dpp(0, __float_as_int(v), 0x141, 0xF, 0xF, true));
    v += __int_as_float(__builtin_amdgcn_update_dpp(0, __float_as_int(v), 0x140, 0xF, 0xF, true));
    return v;
}

// -------- Kernel 1: normalize rows -> bf16; block 0 also: label hist + zero accums --------
__global__ void prep_kernel(const float* __restrict__ feat, unsigned short* __restrict__ fnorm,
                            const int* __restrict__ labels, int* __restrict__ cnt,
                            float* __restrict__ gscal, double* __restrict__ accum,
                            unsigned int* __restrict__ done) {
    if (blockIdx.x == 0) {
        __shared__ int h[NCLS];
        int t = threadIdx.x;
        if (t < NCLS) h[t] = 0;
        if (t == 0) {
            gscal[0] = 0.f; gscal[1] = 0.f;
            accum[0] = 0.0; accum[1] = 0.0; accum[2] = 0.0;
            *done = 0u;
        }
        __syncthreads();
        for (int r = t; r < B_N; r += 256) atomicAdd(&h[labels[r]], 1);
        __syncthreads();
        if (t < NCLS) cnt[t] = h[t];
    }
    int wave = threadIdx.x >> 6, lane = threadIdx.x & 63;
    int row = blockIdx.x * 4 + wave;
    float4 v = *(const float4*)(feat + (size_t)row * D_K + lane * 4);
    float ss = v.x * v.x + v.y * v.y + v.z * v.z + v.w * v.w;
    #pragma unroll
    for (int off = 1; off < 64; off <<= 1) ss += __shfl_xor(ss, off);
    float inv = 1.0f / fmaxf(sqrtf(ss), 1e-12f);
    ushort4 o;
    o.x = f2bf(v.x * inv); o.y = f2bf(v.y * inv);
    o.z = f2bf(v.z * inv); o.w = f2bf(v.w * inv);
    *(ushort4*)(fnorm + (size_t)row * D_K + lane * 4) = o;
}

// -------- Kernel 2: upper-triangular sim tiles; double-buffered K-loop; DPP epilogue --------
// Staging LDS[r][c] = global chunk (c ^ (r&7)): XOR swizzle keeps global_load_lds linear
// while making fragment reads conflict-free.  (512,4): proven no-spill shape (r5/r10).
// Dbuf: prefetch kc+1 issued right AFTER the barrier, so the next barrier's vmcnt(0)
// drain has the whole compute phase to cover it.
__global__ __launch_bounds__(NT, 4) void main_kernel(
        const unsigned short* __restrict__ fnorm, const int* __restrict__ labels,
        float2* __restrict__ G, float* __restrict__ gscal) {
    int bid = blockIdx.x;
    int b = (int)((sqrtf(8.0f * bid + 1.0f) - 1.0f) * 0.5f);
    while ((b + 1) * (b + 2) / 2 <= bid) ++b;
    while (b * (b + 1) / 2 > bid) --b;
    int a = bid - b * (b + 1) / 2;
    const int row0 = a * TILE, col0 = b * TILE;
    const bool diag = (a == b);

    __shared__ short As[2][TILE * 64];    // 2x16 KB; As[0] reused as Rbuf in epilogue
    __shared__ short Bs[2][TILE * 64];    // 2x16 KB; Bs[0] reused as Cbuf
    __shared__ int Ls[2 * TILE];
    __shared__ int ghs[8];
    __shared__ float gps[8];

    const int tid = threadIdx.x;
    const int lane = tid & 63, wave = tid >> 6;
    const int wm = wave >> 2, wn = wave & 3;    // 2 (row) x 4 (col) waves; each 64x32
    const int l15 = lane & 15, lhi = lane >> 4;
    const short* fn = (const short*)fnorm;

    // per-thread staging coordinates (constant across kc)
    const int id0 = tid, id1 = tid + NT;
    const int r0s = id0 >> 3, c0s = (id0 & 7) ^ (r0s & 7), u0 = (id0 & ~63) * 8;
    const int r1s = id1 >> 3, c1s = (id1 & 7) ^ (r1s & 7), u1 = (id1 & ~63) * 8;

    if (tid < 128) Ls[tid] = labels[row0 + tid];
    else if (tid < 256) Ls[tid] = labels[col0 + tid - 128];
    if (lane == 0) ghs[wave] = 0;

    // prologue: stage kc=0 into buffer 0
    {
        gload_lds16(fn + (size_t)(row0 + r0s) * D_K + c0s * 8, &As[0][u0]);
        gload_lds16(fn + (size_t)(row0 + r1s) * D_K + c1s * 8, &As[0][u1]);
        if (!diag) {
            gload_lds16(fn + (size_t)(col0 + r0s) * D_K + c0s * 8, &Bs[0][u0]);
            gload_lds16(fn + (size_t)(col0 + r1s) * D_K + c1s * 8, &Bs[0][u1]);
        }
    }

    f32x4 acc[4][2];
    #pragma unroll
    for (int i = 0; i < 4; i++)
        #pragma unroll
        for (int j = 0; j < 2; j++) acc[i][j] = {0.f, 0.f, 0.f, 0.f};

    #pragma unroll
    for (int kc = 0; kc < 4; ++kc) {
        const int cur = kc & 1;
        __syncthreads();   // drains own DMA (vmcnt 0) -> buf[cur] ready; protects buf reuse
        if (kc < 3) {      // prefetch kc+1 into the other buffer; lands during compute below
            const int nxt = cur ^ 1, ko = (kc + 1) * 64;
            gload_lds16(fn + (size_t)(row0 + r0s) * D_K + ko + c0s * 8, &As[nxt][u0]);
            gload_lds16(fn + (size_t)(row0 + r1s) * D_K + ko + c1s * 8, &As[nxt][u1]);
            if (!diag) {
                gload_lds16(fn + (size_t)(col0 + r0s) * D_K + ko + c0s * 8, &Bs[nxt][u0]);
                gload_lds16(fn + (size_t)(col0 + r1s) * D_K + ko + c1s * 8, &Bs[nxt][u1]);
            }
        }
        const short* Asrc = As[cur];
        const short* Bsrc = diag ? As[cur] : Bs[cur];
        #pragma unroll
        for (int ks = 0; ks < 2; ++ks) {
            short8 af[4], bfr[2];
            #pragma unroll
            for (int mi = 0; mi < 4; mi++) {
                int row = wm * 64 + mi * 16 + l15;
                int ch = (ks * 4 + lhi) ^ (l15 & 7);
                af[mi] = *(const short8*)&Asrc[row * 64 + ch * 8];
            }
            #pragma unroll
            for (int ni = 0; ni < 2; ni++) {
                int row = wn * 32 + ni * 16 + l15;
                int ch = (ks * 4 + lhi) ^ (l15 & 7);
                bfr[ni] = *(const short8*)&Bsrc[row * 64 + ch * 8];
            }
            #pragma unroll
            for (int mi = 0; mi < 4; mi++)
                #pragma unroll
                for (int ni = 0; ni < 2; ni++)
                    acc[mi][ni] = __builtin_amdgcn_mfma_f32_16x16x32_bf16(af[mi], bfr[ni], acc[mi][ni], 0, 0, 0);
        }
    }
    __syncthreads();   // all kc=3 reads done before Rbuf/Cbuf reuse

    // ---- Epilogue. C/D layout: col = lane&15, row = (lane>>4)*4 + reg ----
    float2* Rbuf = (float2*)As[0];   // [wn 0..3][128]
    float2* Cbuf = (float2*)Bs[0];   // [wm 0..1][128]

    int lc[2], colg[2];
    #pragma unroll
    for (int ni = 0; ni < 2; ni++) {
        int c = wn * 32 + ni * 16 + l15;
        lc[ni] = Ls[128 + c];
        colg[ni] = col0 + c;
    }

    float cD[2] = {0.f, 0.f};
    float gp = 0.f;           // sum of positive-pair dots (this tile)
    unsigned int hmask = 0;   // bit (pair*2+ni) = high

    #pragma unroll
    for (int mi = 0; mi < 4; mi++) {
        #pragma unroll
        for (int reg = 0; reg < 4; reg++) {
            int rloc = wm * 64 + mi * 16 + lhi * 4 + reg;
            int rowg = row0 + rloc;
            int lr = Ls[rloc];
            float d = 0.f;
            #pragma unroll
            for (int ni = 0; ni < 2; ni++) {
                float dot = acc[mi][ni][reg];
                float e = __builtin_exp2f((dot - 1.0f) * KEXP);   // e^(sim-20), sim<=20
                bool ns = (rowg != colg[ni]);
                float ev = ns ? e : 0.f;
                d += ev; cD[ni] += ev;
                bool ps = ns && (lr == lc[ni]);
                gp += ps ? dot : 0.f;
                bool hi = ps && (dot > 0.7f);
                hmask |= hi ? (1u << ((mi * 4 + reg) * 2 + ni)) : 0u;
            }
            d = row_sum16(d);                  // VALU pipe, not LDS pipe
            if (l15 == 0) Rbuf[wn * 128 + rloc] = {d, 0.f};
        }
    }

    if (!diag) {
        #pragma unroll
        for (int ni = 0; ni < 2; ni++) {
            cD[ni] += __shfl_xor(cD[ni], 16);
            cD[ni] += __shfl_xor(cD[ni], 32);
        }
        if (lhi == 0) {
            #pragma unroll
            for (int ni = 0; ni < 2; ni++)
                Cbuf[wm * 128 + wn * 32 + ni * 16 + l15] = {cD[ni], 0.f};
        }
    }

    // gp wave reduction: DPP within 16, shuffles across
    gp = row_sum16(gp);
    gp += __shfl_xor(gp, 16);
    gp += __shfl_xor(gp, 32);
    if (lane == 0) gps[wave] = gp;

    // ---- Rare path: any high-similarity positive in this wave ----
    if (__any(hmask != 0)) {
        float cR[2] = {0.f, 0.f};
        #pragma unroll
        for (int mi = 0; mi < 4; mi++) {
            #pragma unroll
            for (int reg = 0; reg < 4; reg++) {
                int rloc = wm * 64 + mi * 16 + lhi * 4 + reg;
                float rx = 0.f;
                #pragma unroll
                for (int ni = 0; ni < 2; ni++) {
                    if (hmask & (1u << ((mi * 4 + reg) * 2 + ni))) {
                        float e = __builtin_exp2f((acc[mi][ni][reg] - 1.0f) * KEXP);
                        rx += e; cR[ni] += e;
                    }
                }
                rx = row_sum16(rx);
                if (l15 == 0) Rbuf[wn * 128 + rloc].y = rx;
            }
        }
        if (!diag) {
            #pragma unroll
            for (int ni = 0; ni < 2; ni++) {
                cR[ni] += __shfl_xor(cR[ni], 16);
                cR[ni] += __shfl_xor(cR[ni], 32);
            }
            if (lhi == 0) {
                #pragma unroll
                for (int ni = 0; ni < 2; ni++)
                    Cbuf[wm * 128 + wn * 32 + ni * 16 + l15].y = cR[ni];
            }
        }
        int nhi = __popc(hmask);
        #pragma unroll
        for (int off = 1; off < 64; off <<= 1) nhi += __shfl_xor(nhi, off);
        if (lane == 0) ghs[wave] = nhi;
    }
    __syncthreads();

    if (tid < 128) {
        int r = tid;
        float2 a0 = Rbuf[r], a1 = Rbuf[128 + r], a2 = Rbuf[256 + r], a3 = Rbuf[384 + r];
        G[(size_t)b * B_N + row0 + r] = {a0.x + a1.x + a2.x + a3.x, a0.y + a1.y + a2.y + a3.y};
    } else if (tid < 256 && !diag) {
        int c = tid - 128;
        float2 a0 = Cbuf[c], a1 = Cbuf[128 + c];
        G[(size_t)a * B_N + col0 + c] = {a0.x + a1.x, a0.y + a1.y};
    }
    if (tid == 0) {
        float w = diag ? 1.0f : 2.0f;   // off-diag tile stands for (i,j) and (j,i)
        float gpt = gps[0] + gps[1] + gps[2] + gps[3] + gps[4] + gps[5] + gps[6] + gps[7];
        atomicAdd(&gscal[0], w * gpt);
        int tot = ghs[0] + ghs[1] + ghs[2] + ghs[3] + ghs[4] + ghs[5] + ghs[6] + ghs[7];
        if (tot > 0) atomicAdd(&gscal[1], w * (float)tot);
    }
}

// -------- Kernel 3: per-row reduction over 64 slots + last-block final assembly --------
__global__ void finalize_kernel(const float2* __restrict__ G, const int* __restrict__ labels,
                                const int* __restrict__ cnt, const float* __restrict__ gscal,
                                double* __restrict__ accum, unsigned int* __restrict__ done,
                                float* __restrict__ out) {
    int lane = threadIdx.x & 63, q = threadIdx.x >> 6;   // q = slot quarter
    int r = blockIdx.x * 64 + lane;
    float d = 0.f, rx = 0.f;
    #pragma unroll
    for (int s = 0; s < 16; ++s) {
        float2 g = G[(size_t)(q * 16 + s) * B_N + r];
        d += g.x; rx += g.y;
    }
    __shared__ float2 sh[4][64];
    sh[q][lane] = {d, rx};
    __syncthreads();
    if (threadIdx.x < 64) {
        int rr = blockIdx.x * 64 + threadIdx.x;
        float2 t0 = sh[0][threadIdx.x], t1 = sh[1][threadIdx.x];
        float2 t2 = sh[2][threadIdx.x], t3 = sh[3][threadIdx.x];
        float dd = t0.x + t1.x + t2.x + t3.x;
        float rr2 = t0.y + t1.y + t2.y + t3.y;
        float np = (float)(cnt[labels[rr]] - 1);
        float ld = logf(dd + 1e-12f) + 20.0f;             // log_denom (shift 20)
        double s1 = (double)np * (double)ld;
        double s2 = (double)np;
        double s3 = (rr2 > 0.f) ? (double)logf(rr2 + 1.0f) : 0.0;  // baseline=0: sim_max=20
        #pragma unroll
        for (int off = 1; off < 64; off <<= 1) {
            s1 += __shfl_xor(s1, off);
            s2 += __shfl_xor(s2, off);
            s3 += __shfl_xor(s3, off);
        }
        if (threadIdx.x == 0) {
            atomicAdd(&accum[0], s1);
            atomicAdd(&accum[1], s2);
            atomicAdd(&accum[2], s3);
            __threadfence();
            unsigned int tk = atomicAdd(done, 1u);
            if (tk == gridDim.x - 1) {           // last block assembles the scalar
                double a1 = atomicAdd(&accum[0], 0.0);
                double a2 = atomicAdd(&accum[1], 0.0);
                double a3 = atomicAdd(&accum[2], 0.0);
                double gp = (double)gscal[0];    // sum over ordered pos pairs of dot
                double gh = (double)gscal[1];    // count of high ordered pairs
                double scl = (a2 > 0.0) ? (a1 - 20.0 * gp) / fmax(a2, 1.0) : 0.0;
                double rel = (gh > 0.0) ? a3 / fmax(gh, 1.0) : 0.0;
                double tot = scl + rel;          // BETA = 1.0
                tot = fmin(fmax(tot, 0.0), 10.0);
                out[0] = (float)tot;
            }
        }
    }
}

extern "C" void kernel_launch(void* const* d_in, const int* in_sizes, int n_in,
                              void* d_out, int out_size, void* d_ws, size_t ws_size,
                              hipStream_t stream) {
    const float* feat = (const float*)d_in[0];
    const int* labels = (const int*)d_in[1];
    float* out = (float*)d_out;
    char* ws = (char*)d_ws;

    unsigned short* fnorm = (unsigned short*)(ws);                          // 4 MB
    float2* G          = (float2*)(ws + (size_t)4 * 1024 * 1024);           // 4 MB: [64][8192]
    int*    cnt        = (int*)(ws + (size_t)8 * 1024 * 1024);              // 400 B
    float*  gscal      = (float*)(ws + (size_t)8 * 1024 * 1024 + 1024);     // 8 B
    double* accum      = (double*)(ws + (size_t)8 * 1024 * 1024 + 2048);    // 24 B
    unsigned int* done = (unsigned int*)(ws + (size_t)8 * 1024 * 1024 + 3072); // 4 B

    prep_kernel<<<B_N / 4, 256, 0, stream>>>(feat, fnorm, labels, cnt, gscal, accum, done);
    main_kernel<<<NPAIR, NT, 0, stream>>>(fnorm, labels, G, gscal);
    finalize_kernel<<<B_N / 64, 256, 0, stream>>>(G, labels, cnt, gscal, accum, done, out);
    (void)in_sizes; (void)n_in; (void)out_size; (void)ws_size;
}